// Round 5
// baseline (634.932 us; speedup 1.0000x reference)
//
#include <hip/hip_runtime.h>
#include <math.h>

#define BB 32
#define NN 16384
#define GG 128
#define KK 64
#define HH 128
#define DD 384
#define LN_EPS 1e-5f
#define CANDCAP 2560

// round-to-nearest sum of 3 squares, matching jnp.sum(x**2, -1) order, no FMA contraction
__device__ __forceinline__ float sq3(float x, float y, float z) {
    return __fadd_rn(__fadd_rn(__fmul_rn(x, x), __fmul_rn(y, y)), __fmul_rn(z, z));
}

// order-preserving uint key of dist2, same formula/rounding as reference
__device__ __forceinline__ unsigned distkey(float px, float py, float pz, float4 c4) {
    float p2 = sq3(px, py, pz);
    float dot = __fadd_rn(__fadd_rn(__fmul_rn(c4.x, px), __fmul_rn(c4.y, py)),
                          __fmul_rn(c4.z, pz));
    float d = __fsub_rn(__fadd_rn(c4.w, p2), __fmul_rn(2.0f, dot));
    unsigned u = __float_as_uint(d);
    return u ^ ((u & 0x80000000u) ? 0xFFFFFFFFu : 0x80000000u);
}

// ---- in-wave bitonic: sort 64 (key,idx) pairs ascending lexicographic ----
__device__ __forceinline__ void sort64(unsigned& k, unsigned& i) {
    const int lane = threadIdx.x & 63;
#pragma unroll
    for (int m = 2; m <= 64; m <<= 1) {
#pragma unroll
        for (int j = m >> 1; j > 0; j >>= 1) {
            unsigned ok = __shfl_xor(k, j, 64);
            unsigned oi = __shfl_xor(i, j, 64);
            bool lt = (ok < k) || (ok == k && oi < i);
            bool low = ((lane & j) == 0);
            bool asc = ((lane & m) == 0);
            if ((low == asc) ? lt : !lt) { k = ok; i = oi; }
        }
    }
}

// ---- merge two sorted-64 runs, keep the 64 smallest, sorted (in A) ----
__device__ __forceinline__ void merge64(unsigned& k, unsigned& i, unsigned kB, unsigned iB) {
    const int lane = threadIdx.x & 63;
    unsigned rk = __shfl(kB, 63 - lane, 64);
    unsigned ri = __shfl(iB, 63 - lane, 64);
    bool lt = (rk < k) || (rk == k && ri < i);
    if (lt) { k = rk; i = ri; }  // lower half of bitonic merge = 64 smallest
#pragma unroll
    for (int j = 32; j > 0; j >>= 1) {  // cleanup: sort the bitonic lower half
        unsigned ok = __shfl_xor(k, j, 64);
        unsigned oi = __shfl_xor(i, j, 64);
        bool l2 = (ok < k) || (ok == k && oi < i);
        bool low = ((lane & j) == 0);
        if (low ? l2 : !l2) { k = ok; i = oi; }
    }
}

// ---------------- prep: transpose w2 [128,384] -> w2t [384,128] ----------------
__global__ void prep_kernel(const float* __restrict__ w2, float* __restrict__ w2t) {
    int i = blockIdx.x * 256 + threadIdx.x;
    if (i < HH * DD) {
        int f = i >> 7;
        int k = i & 127;
        w2t[i] = w2[k * DD + f];
    }
}

// ---------------- FPS: one block per batch, 1024 threads, 16 pts/thread ----------------
// R4 post-mortem: array-typed point/dist caches were never promoted (VGPR=84, scratch
// round-trip every iteration). Named scalars are SSA values -> true register residency.
#define FPS_DECL(r) float x##r, y##r, z##r, d##r;
#define FPS_LOAD(j, r0, r1, r2, r3)                                        \
    {                                                                      \
        int q = (j)*1024 + tid;                                            \
        float4 A = p4[3 * q], B = p4[3 * q + 1], C = p4[3 * q + 2];        \
        x##r0 = A.x; y##r0 = A.y; z##r0 = A.z;                             \
        x##r1 = A.w; y##r1 = B.x; z##r1 = B.y;                             \
        x##r2 = B.z; y##r2 = B.w; z##r2 = C.x;                             \
        x##r3 = C.y; y##r3 = C.z; z##r3 = C.w;                             \
        d##r0 = INFINITY; d##r1 = INFINITY; d##r2 = INFINITY; d##r3 = INFINITY; \
    }
#define FPS_UPD(r, base, c)                                                \
    {                                                                      \
        float dx = __fsub_rn(x##r, cx);                                    \
        float dy = __fsub_rn(y##r, cy);                                    \
        float dz = __fsub_rn(z##r, cz);                                    \
        float dd = sq3(dx, dy, dz);                                        \
        float dj = fminf(d##r, dd);                                        \
        d##r = dj;                                                         \
        if (dj > bv##c) { bv##c = dj; bi##c = (base) + 4 * tid; }          \
    }

__global__ __launch_bounds__(1024, 4) void fps_kernel(const float* __restrict__ pts,
                                                      float* __restrict__ cent_out,
                                                      float4* __restrict__ cent_pad) {
    const int b = blockIdx.x;
    const int tid = threadIdx.x;
    const float* p = pts + (size_t)b * NN * 3;
    const float4* p4 = (const float4*)p;

    FPS_DECL(0) FPS_DECL(1) FPS_DECL(2) FPS_DECL(3)
    FPS_DECL(4) FPS_DECL(5) FPS_DECL(6) FPS_DECL(7)
    FPS_DECL(8) FPS_DECL(9) FPS_DECL(10) FPS_DECL(11)
    FPS_DECL(12) FPS_DECL(13) FPS_DECL(14) FPS_DECL(15)
    FPS_LOAD(0, 0, 1, 2, 3)
    FPS_LOAD(1, 4, 5, 6, 7)
    FPS_LOAD(2, 8, 9, 10, 11)
    FPS_LOAD(3, 12, 13, 14, 15)

    __shared__ unsigned long long slot[GG];  // one pre-zeroed slot per iteration
    for (int i = tid; i < GG; i += 1024) slot[i] = 0ull;
    __syncthreads();

    float cx = p[0], cy = p[1], cz = p[2];  // deterministic start at index 0

    for (int it = 0; it < GG; it++) {
        if (tid == 0) {
            float* co = cent_out + ((size_t)b * GG + it) * 3;
            co[0] = cx; co[1] = cy; co[2] = cz;
            cent_pad[b * GG + it] = make_float4(cx, cy, cz, sq3(cx, cy, cz));
        }
        if (it == GG - 1) break;  // last argmax unused

        float bv0 = -INFINITY, bv1 = -INFINITY, bv2 = -INFINITY, bv3 = -INFINITY;
        int bi0 = 0, bi1 = 0, bi2 = 0, bi3 = 0;
        FPS_UPD(0, 0, 0)      FPS_UPD(1, 1, 1)      FPS_UPD(2, 2, 2)      FPS_UPD(3, 3, 3)
        FPS_UPD(4, 4096, 0)   FPS_UPD(5, 4097, 1)   FPS_UPD(6, 4098, 2)   FPS_UPD(7, 4099, 3)
        FPS_UPD(8, 8192, 0)   FPS_UPD(9, 8193, 1)   FPS_UPD(10, 8194, 2)  FPS_UPD(11, 8195, 3)
        FPS_UPD(12, 12288, 0) FPS_UPD(13, 12289, 1) FPS_UPD(14, 12290, 2) FPS_UPD(15, 12291, 3)

        float fv = bv0; int fi = bi0;
        if (bv1 > fv || (bv1 == fv && bi1 < fi)) { fv = bv1; fi = bi1; }
        if (bv2 > fv || (bv2 == fv && bi2 < fi)) { fv = bv2; fi = bi2; }
        if (bv3 > fv || (bv3 == fv && bi3 < fi)) { fv = bv3; fi = bi3; }
#pragma unroll
        for (int off = 32; off >= 1; off >>= 1) {
            float ov = __shfl_down(fv, off);
            int oi = __shfl_down(fi, off);
            if (ov > fv || (ov == fv && oi < fi)) { fv = ov; fi = oi; }
        }
        // dist >= 0 so float bits are order-monotone; ~idx -> lowest index wins max
        if ((tid & 63) == 0) {
            unsigned long long packed =
                ((unsigned long long)__float_as_uint(fv) << 32) |
                (unsigned)(0xFFFFFFFFu - (unsigned)fi);
            atomicMax(&slot[it], packed);
        }
        __syncthreads();
        unsigned long long w = slot[it];
        int idx = (int)(0xFFFFFFFFu - (unsigned)w);
        const float* wp = p + (size_t)idx * 3;  // broadcast same-address load, L2-hit
        cx = wp[0]; cy = wp[1]; cz = wp[2];
    }
}

// ---------------- group kernel: sampling select + exact top-64 + MLP + mean + LN ----
__global__ __launch_bounds__(256, 4) void group_kernel(
    const float* __restrict__ pts, const float4* __restrict__ cent_pad,
    const float* __restrict__ w1, const float* __restrict__ b1,
    const float* __restrict__ w2t, const float* __restrict__ b2,
    const float* __restrict__ lns, const float* __restrict__ lnb,
    float* __restrict__ tok_out) {
    __shared__ __align__(16) unsigned long long cand[CANDCAP];  // 20 KB
    __shared__ unsigned long long runLds[256];                  // 2 KB (samples + runs)
    __shared__ int selIdx[KK];
    __shared__ float4 localPt[KK];
    __shared__ float w1s[3 * HH];
    __shared__ float b1s[HH];
    __shared__ __align__(16) float hbar[HH];
    __shared__ float partial[256];
    __shared__ float red2[8];
    __shared__ float toks[DD];
    __shared__ unsigned long long wmin[4];
    __shared__ unsigned T1S, T2S;
    __shared__ int cntS;
    __shared__ unsigned long long lastS;
    __shared__ float muS, rstdS;

    const int tid = threadIdx.x;
    const int lane = tid & 63, wid = tid >> 6;
    // XCD-aware swizzle: each XCD sees only 4 batches' points (768KB -> L2 resident)
    int bid = blockIdx.x;
    int xcd = bid & 7, sub = bid >> 3;
    int b = xcd * 4 + (sub >> 7);
    int g = sub & 127;

    const float* p = pts + (size_t)b * NN * 3;
    const float4* p4 = (const float4*)p;
    float4 c4 = cent_pad[b * GG + g];

    for (int i = tid; i < 3 * HH; i += 256) w1s[i] = w1[i];
    if (tid < HH) b1s[tid] = b1[tid];
    if (tid == 0) cntS = 0;

    // ---- sampling: 256 keys (one per thread), per-wave sort + merge -> T1/T2
    {
        int sn = tid << 6;  // sample point index
        unsigned sk = distkey(p[sn * 3], p[sn * 3 + 1], p[sn * 3 + 2], c4);
        unsigned si = (unsigned)sn;
        sort64(sk, si);  // each wave sorts its own 64 samples
        runLds[tid] = ((unsigned long long)sk << 32) | si;
        __syncthreads();
        if (wid == 0) {
            unsigned ak = sk, ai = si;  // wave0's sorted run
#pragma unroll
            for (int w = 1; w < 4; w++) {
                unsigned long long v = runLds[w * 64 + lane];
                merge64(ak, ai, (unsigned)(v >> 32), (unsigned)v);
            }
            if (lane == 7) T1S = ak;    // 8th smallest sample key  (E[cnt]~512)
            if (lane == 63) T2S = ak;   // 64th smallest -> guarantees cnt>=64
        }
        __syncthreads();
    }

#define COLLECT(TT)                                                            \
    for (int i = 0; i < 16; i++) {                                             \
        int t4 = i * 256 + tid;                                                \
        float4 A = p4[3 * t4], Bv = p4[3 * t4 + 1], Cv = p4[3 * t4 + 2];       \
        unsigned kks[4];                                                       \
        kks[0] = distkey(A.x, A.y, A.z, c4);                                   \
        kks[1] = distkey(A.w, Bv.x, Bv.y, c4);                                 \
        kks[2] = distkey(Bv.z, Bv.w, Cv.x, c4);                                \
        kks[3] = distkey(Cv.y, Cv.z, Cv.w, c4);                                \
        _Pragma("unroll") for (int q = 0; q < 4; q++) {                        \
            if (kks[q] <= (TT)) {                                              \
                int pos = atomicAdd(&cntS, 1);                                 \
                if (pos < CANDCAP)                                             \
                    cand[pos] = ((unsigned long long)kks[q] << 32) |           \
                                (unsigned)(4 * t4 + q);                        \
            }                                                                  \
        }                                                                      \
    }

    unsigned T1 = T1S;
    COLLECT(T1)
    __syncthreads();
    int cnt = cntS;

    if (cnt < KK) {  // rare escalation (P ~ 1e-6): T2 guarantees >= 64
        if (tid == 0) cntS = 0;
        __syncthreads();
        unsigned T2 = T2S;
        COLLECT(T2)
        __syncthreads();
        cnt = cntS;
    }

    if (cnt >= KK && cnt <= 1024) {
        // ---- exact top-64 via per-wave bitonic sort + merge-keep-64 (register shuffles)
        unsigned ak, ai;
#pragma unroll
        for (int r = 0; r < 4; r++) {
            int slot16 = (wid * 4 + r) * 64 + lane;
            unsigned ck = 0xFFFFFFFFu, ci = 0xFFFFFFFFu;  // sentinel > any real pair
            if (slot16 < cnt) {
                unsigned long long v = cand[slot16];
                ck = (unsigned)(v >> 32); ci = (unsigned)v;
            }
            sort64(ck, ci);
            if (r == 0) { ak = ck; ai = ci; }
            else merge64(ak, ai, ck, ci);
        }
        runLds[tid] = ((unsigned long long)ak << 32) | ai;
        __syncthreads();
        if (wid == 0) {
#pragma unroll
            for (int w = 1; w < 4; w++) {
                unsigned long long v = runLds[w * 64 + lane];
                merge64(ak, ai, (unsigned)(v >> 32), (unsigned)v);
            }
            selIdx[lane] = (int)ai;  // sorted ascending by (key,idx) == top_k order
        }
        __syncthreads();
    } else if (cnt >= KK && cnt <= CANDCAP) {
        // ---- mid-size path: exact pairwise rank-select
        for (int c0 = tid; c0 < cnt; c0 += 256) {
            unsigned long long pr = cand[c0];
            int rank = 0;
            for (int j = 0; j < cnt; j++) rank += (cand[j] < pr);
            if (rank < KK) selIdx[rank] = (int)(unsigned)pr;
        }
        __syncthreads();
    } else {
        // ---- pathological fallback: exact 64-round min-extraction with recompute
        if (tid == 0) lastS = 0ull;
        __syncthreads();
        for (int r = 0; r < KK; r++) {
            unsigned long long last = lastS;
            unsigned long long best = 0xFFFFFFFFFFFFFFFFull;
            for (int i = 0; i < 16; i++) {
                int t4 = i * 256 + tid;
                float4 A = p4[3 * t4], Bv = p4[3 * t4 + 1], Cv = p4[3 * t4 + 2];
                unsigned kks[4];
                kks[0] = distkey(A.x, A.y, A.z, c4);
                kks[1] = distkey(A.w, Bv.x, Bv.y, c4);
                kks[2] = distkey(Bv.z, Bv.w, Cv.x, c4);
                kks[3] = distkey(Cv.y, Cv.z, Cv.w, c4);
#pragma unroll
                for (int q = 0; q < 4; q++) {
                    unsigned long long pr =
                        ((unsigned long long)kks[q] << 32) | (unsigned)(4 * t4 + q);
                    if ((r == 0 || pr > last) && pr < best) best = pr;
                }
            }
            unsigned blo = (unsigned)best, bhi = (unsigned)(best >> 32);
#pragma unroll
            for (int off = 32; off >= 1; off >>= 1) {
                unsigned olo = __shfl_down(blo, off);
                unsigned ohi = __shfl_down(bhi, off);
                unsigned long long ob = ((unsigned long long)ohi << 32) | olo;
                unsigned long long cur = ((unsigned long long)bhi << 32) | blo;
                if (ob < cur) { blo = olo; bhi = ohi; }
            }
            if (lane == 0) wmin[wid] = ((unsigned long long)bhi << 32) | blo;
            __syncthreads();
            if (tid == 0) {
                unsigned long long m = wmin[0];
                for (int w = 1; w < 4; w++) if (wmin[w] < m) m = wmin[w];
                selIdx[r] = (int)(unsigned)m;
                lastS = m;
            }
            __syncthreads();
        }
    }

    // ---- gather + local coords
    if (tid < KK) {
        int n = selIdx[tid];
        float px = p[n * 3], py = p[n * 3 + 1], pz = p[n * 3 + 2];
        localPt[tid] = make_float4(px - c4.x, py - c4.y, pz - c4.z, 0.f);
    }
    __syncthreads();
    // ---- layer1 + exact GELU + mean over K (2 threads per feature, 32 pts each)
    {
        int f = tid & 127, half = tid >> 7;
        float wa = w1s[f], wb = w1s[HH + f], wc = w1s[2 * HH + f], bb = b1s[f];
        float s = 0.f;
        for (int k = half * 32; k < half * 32 + 32; k++) {
            float4 lp = localPt[k];
            float a = lp.x * wa + lp.y * wb + lp.z * wc + bb;
            float hh = 0.5f * a * (1.0f + erff(a * 0.70710678118654752440f));
            s += hh;
        }
        partial[tid] = s;
    }
    __syncthreads();
    if (tid < HH) hbar[tid] = (partial[tid] + partial[tid + HH]) * (1.0f / 64.0f);
    __syncthreads();
    // ---- layer2: tokens = hbar @ w2 + b2   (mean commutes with the linear layer)
    for (int f2 = tid; f2 < DD; f2 += 256) {
        const float4* wrow = (const float4*)(w2t + f2 * HH);
        const float4* hb = (const float4*)hbar;
        float acc = b2[f2];
#pragma unroll 8
        for (int q = 0; q < 32; q++) {
            float4 w4 = wrow[q];
            float4 h4 = hb[q];
            acc += h4.x * w4.x + h4.y * w4.y + h4.z * w4.z + h4.w * w4.w;
        }
        toks[f2] = acc;
    }
    __syncthreads();
    // ---- LayerNorm over 384
    {
        float s1 = 0.f, s2 = 0.f;
        for (int f2 = tid; f2 < DD; f2 += 256) {
            float v = toks[f2];
            s1 += v;
            s2 += v * v;
        }
#pragma unroll
        for (int off = 32; off >= 1; off >>= 1) {
            s1 += __shfl_down(s1, off);
            s2 += __shfl_down(s2, off);
        }
        if (lane == 0) { partial[wid] = s1; red2[wid] = s2; }
        __syncthreads();
        if (tid == 0) {
            float t1 = partial[0] + partial[1] + partial[2] + partial[3];
            float t2 = red2[0] + red2[1] + red2[2] + red2[3];
            float mu = t1 / (float)DD;
            float var = t2 / (float)DD - mu * mu;
            muS = mu;
            rstdS = rsqrtf(var + LN_EPS);
        }
        __syncthreads();
    }
    float mu = muS, rstd = rstdS;
    float* outp = tok_out + ((size_t)b * GG + g) * DD;
    for (int f2 = tid; f2 < DD; f2 += 256) {
        outp[f2] = (toks[f2] - mu) * rstd * lns[f2] + lnb[f2];
    }
}

extern "C" void kernel_launch(void* const* d_in, const int* in_sizes, int n_in,
                              void* d_out, int out_size, void* d_ws, size_t ws_size,
                              hipStream_t stream) {
    const float* pts = (const float*)d_in[0];
    const float* w1 = (const float*)d_in[1];
    const float* b1 = (const float*)d_in[2];
    const float* w2 = (const float*)d_in[3];
    const float* b2 = (const float*)d_in[4];
    const float* lns = (const float*)d_in[5];
    const float* lnb = (const float*)d_in[6];
    float* out = (float*)d_out;

    // ws layout: cent_pad [B*G float4] = 64KB, then w2t [384*128 floats] = 192KB
    float4* cent_pad = (float4*)d_ws;
    float* w2t = (float*)((char*)d_ws + BB * GG * sizeof(float4));

    prep_kernel<<<192, 256, 0, stream>>>(w2, w2t);
    fps_kernel<<<BB, 1024, 0, stream>>>(pts, out, cent_pad);
    group_kernel<<<BB * GG, 256, 0, stream>>>(pts, cent_pad, w1, b1, w2t, b2, lns, lnb,
                                              out + BB * GG * 3);
}